// Round 1
// baseline (2239.955 us; speedup 1.0000x reference)
//
#include <hip/hip_runtime.h>
#include <math.h>

#define NEG_SLOPE 0.01f

// ---------------- degree kernels ----------------
__global__ __launch_bounds__(256) void deg_kernel(const int* __restrict__ src,
    const int* __restrict__ dst, float* __restrict__ outdeg,
    float* __restrict__ indeg, int E)
{
    int i = blockIdx.x * 256 + threadIdx.x;
    if (i < E) {
        atomicAdd(&outdeg[src[i]], 1.0f);
        atomicAdd(&indeg[dst[i]], 1.0f);
    }
}

__global__ __launch_bounds__(256) void finalize_deg(float* __restrict__ a, int n)
{
    int i = blockIdx.x * 256 + threadIdx.x;
    if (i < n) a[i] = 1.0f / sqrtf(fmaxf(a[i], 1.0f));
}

// out[i*128+j] = ba[j] (+ bb[j]) ; total = M*128
__global__ __launch_bounds__(256) void init_bias2(float* __restrict__ out,
    const float* __restrict__ ba, const float* __restrict__ bb, int total)
{
    int i = blockIdx.x * 256 + threadIdx.x;
    if (i < total) {
        int j = i & 127;
        float v = ba[j];
        if (bb) v += bb[j];
        out[i] = v;
    }
}

// ---------------- SGEMM: C[M,128] = f(A[M,128]) * inv_s[row] @ W[128,128] ----------------
// BM=64, BN=64, BK=16, 256 threads, 4x4 per thread. RELU: leaky-relu A before scale.
template <int RELU>
__global__ __launch_bounds__(256) void sgemm128(const float* __restrict__ A,
    const float* __restrict__ W, const float* __restrict__ inv_s,
    float* __restrict__ C, int M)
{
    __shared__ float As[16][65];
    __shared__ float Bs[16][65];
    const int tid  = threadIdx.x;
    const int row0 = blockIdx.x * 64;
    const int col0 = blockIdx.y * 64;
    const int tr = tid >> 4;          // 0..15
    const int tc = tid & 15;          // 0..15
    const int a_row = tid >> 2;       // 0..63
    const int a_k4  = (tid & 3) << 2; // 0,4,8,12
    const int b_krow = tid >> 4;      // 0..15
    const int b_c    = (tid & 15) << 2;

    float acc[4][4] = {};
    const int arow_g = row0 + a_row;
    float scale = 0.0f;
    if (arow_g < M) scale = inv_s[arow_g];

    for (int k0 = 0; k0 < 128; k0 += 16) {
        float4 av = make_float4(0.f, 0.f, 0.f, 0.f);
        if (arow_g < M)
            av = *(const float4*)(A + arow_g * 128 + k0 + a_k4);
        if (RELU) {
            av.x = av.x >= 0.f ? av.x : av.x * NEG_SLOPE;
            av.y = av.y >= 0.f ? av.y : av.y * NEG_SLOPE;
            av.z = av.z >= 0.f ? av.z : av.z * NEG_SLOPE;
            av.w = av.w >= 0.f ? av.w : av.w * NEG_SLOPE;
        }
        As[a_k4 + 0][a_row] = av.x * scale;
        As[a_k4 + 1][a_row] = av.y * scale;
        As[a_k4 + 2][a_row] = av.z * scale;
        As[a_k4 + 3][a_row] = av.w * scale;

        float4 bv = *(const float4*)(W + (k0 + b_krow) * 128 + col0 + b_c);
        Bs[b_krow][b_c + 0] = bv.x;
        Bs[b_krow][b_c + 1] = bv.y;
        Bs[b_krow][b_c + 2] = bv.z;
        Bs[b_krow][b_c + 3] = bv.w;
        __syncthreads();

#pragma unroll
        for (int k = 0; k < 16; ++k) {
            float ar[4], br[4];
#pragma unroll
            for (int i = 0; i < 4; ++i) ar[i] = As[k][tr * 4 + i];
#pragma unroll
            for (int j = 0; j < 4; ++j) br[j] = Bs[k][tc * 4 + j];
#pragma unroll
            for (int i = 0; i < 4; ++i)
#pragma unroll
                for (int j = 0; j < 4; ++j)
                    acc[i][j] = fmaf(ar[i], br[j], acc[i][j]);
        }
        __syncthreads();
    }

#pragma unroll
    for (int i = 0; i < 4; ++i) {
        int row = row0 + tr * 4 + i;
        if (row < M) {
            float4 v = make_float4(acc[i][0], acc[i][1], acc[i][2], acc[i][3]);
            *(float4*)(C + row * 128 + col0 + tc * 4) = v;
        }
    }
}

// ---------------- edge scatter: out[dst] += feat[src] * inv_d[dst] ----------------
// one wave (64 lanes) per edge, float2 per lane
__global__ __launch_bounds__(256) void scatter_add(const float* __restrict__ feat,
    const int* __restrict__ src, const int* __restrict__ dst,
    const float* __restrict__ inv_d, float* __restrict__ out, int E)
{
    int lane = threadIdx.x & 63;
    int e = blockIdx.x * 4 + (threadIdx.x >> 6);
    if (e < E) {
        int s = src[e], d = dst[e];
        float w = inv_d[d];
        float2 v = *(const float2*)(feat + (size_t)s * 128 + lane * 2);
        float* o = out + (size_t)d * 128 + lane * 2;
        atomicAdd(o,     v.x * w);
        atomicAdd(o + 1, v.y * w);
    }
}

extern "C" void kernel_launch(void* const* d_in, const int* in_sizes, int n_in,
                              void* d_out, int out_size, void* d_ws, size_t ws_size,
                              hipStream_t stream)
{
    const float* x_chem = (const float*)d_in[0];
    const float* x_gene = (const float*)d_in[1];
    const int* src_cc = (const int*)d_in[2];
    const int* dst_cc = (const int*)d_in[3];
    const int* src_cg = (const int*)d_in[4];
    const int* dst_cg = (const int*)d_in[5];
    const int* src_gc = (const int*)d_in[6];
    const int* dst_gc = (const int*)d_in[7];
    const float* W1_cc = (const float*)d_in[8];
    const float* W1_cg = (const float*)d_in[9];
    const float* W1_gc = (const float*)d_in[10];
    const float* W2_cc = (const float*)d_in[11];
    const float* W2_cg = (const float*)d_in[12];  // unused (h2_gene not returned... cg only feeds h1_gene)
    const float* W2_gc = (const float*)d_in[13];
    const float* b1_cc = (const float*)d_in[14];
    const float* b1_cg = (const float*)d_in[15];
    const float* b1_gc = (const float*)d_in[16];
    const float* b2_cc = (const float*)d_in[17];
    const float* b2_cg = (const float*)d_in[18];  // unused
    const float* b2_gc = (const float*)d_in[19];
    (void)W2_cg; (void)b2_cg; (void)n_in; (void)out_size; (void)ws_size;

    const int Nc = in_sizes[0] / 128;
    const int Ng = in_sizes[1] / 128;
    const int Ecc = in_sizes[2];
    const int Ecg = in_sizes[4];
    const int Egc = in_sizes[6];

    // workspace layout (floats)
    float* ws = (float*)d_ws;
    float* inv_src_cc = ws;                    // Nc
    float* inv_dst_cc = inv_src_cc + Nc;       // Nc
    float* inv_src_cg = inv_dst_cc + Nc;       // Nc
    float* inv_dst_cg = inv_src_cg + Nc;       // Ng
    float* inv_src_gc = inv_dst_cg + Ng;       // Ng
    float* inv_dst_gc = inv_src_gc + Ng;       // Nc
    float* h1_chem = inv_dst_gc + Nc;          // Nc*128
    float* h1_gene = h1_chem + (size_t)Nc * 128;   // Ng*128
    float* tmp     = h1_gene + (size_t)Ng * 128;   // Nc*128
    float* out     = (float*)d_out;

    const int degTotal = 4 * Nc + 2 * Ng;
    hipMemsetAsync(ws, 0, (size_t)degTotal * sizeof(float), stream);

    deg_kernel<<<(Ecc + 255) / 256, 256, 0, stream>>>(src_cc, dst_cc, inv_src_cc, inv_dst_cc, Ecc);
    deg_kernel<<<(Ecg + 255) / 256, 256, 0, stream>>>(src_cg, dst_cg, inv_src_cg, inv_dst_cg, Ecg);
    deg_kernel<<<(Egc + 255) / 256, 256, 0, stream>>>(src_gc, dst_gc, inv_src_gc, inv_dst_gc, Egc);
    finalize_deg<<<(degTotal + 255) / 256, 256, 0, stream>>>(ws, degTotal);

    dim3 blk(256);
    // ---- layer 1 ----
    // h1_chem = b1_cc + b1_gc + agg_cc + agg_gc
    sgemm128<0><<<dim3((Nc + 63) / 64, 2), blk, 0, stream>>>(x_chem, W1_cc, inv_src_cc, tmp, Nc);
    init_bias2<<<(Nc * 128 + 255) / 256, blk, 0, stream>>>(h1_chem, b1_cc, b1_gc, Nc * 128);
    scatter_add<<<(Ecc + 3) / 4, blk, 0, stream>>>(tmp, src_cc, dst_cc, inv_dst_cc, h1_chem, Ecc);

    sgemm128<0><<<dim3((Ng + 63) / 64, 2), blk, 0, stream>>>(x_gene, W1_gc, inv_src_gc, tmp, Ng);
    scatter_add<<<(Egc + 3) / 4, blk, 0, stream>>>(tmp, src_gc, dst_gc, inv_dst_gc, h1_chem, Egc);

    // h1_gene = b1_cg + agg_cg
    sgemm128<0><<<dim3((Nc + 63) / 64, 2), blk, 0, stream>>>(x_chem, W1_cg, inv_src_cg, tmp, Nc);
    init_bias2<<<(Ng * 128 + 255) / 256, blk, 0, stream>>>(h1_gene, b1_cg, nullptr, Ng * 128);
    scatter_add<<<(Ecg + 3) / 4, blk, 0, stream>>>(tmp, src_cg, dst_cg, inv_dst_cg, h1_gene, Ecg);

    // ---- layer 2 (leaky-relu fused into GEMM A-load) ----
    sgemm128<1><<<dim3((Nc + 63) / 64, 2), blk, 0, stream>>>(h1_chem, W2_cc, inv_src_cc, tmp, Nc);
    init_bias2<<<(Nc * 128 + 255) / 256, blk, 0, stream>>>(out, b2_cc, b2_gc, Nc * 128);
    scatter_add<<<(Ecc + 3) / 4, blk, 0, stream>>>(tmp, src_cc, dst_cc, inv_dst_cc, out, Ecc);

    sgemm128<1><<<dim3((Ng + 63) / 64, 2), blk, 0, stream>>>(h1_gene, W2_gc, inv_src_gc, tmp, Ng);
    scatter_add<<<(Egc + 3) / 4, blk, 0, stream>>>(tmp, src_gc, dst_gc, inv_dst_gc, out, Egc);
}

// Round 2
// 691.292 us; speedup vs baseline: 3.2402x; 3.2402x over previous
//
#include <hip/hip_runtime.h>
#include <math.h>

#define NEG_SLOPE 0.01f

// ---------------- degree kernel (int histogram) ----------------
__global__ __launch_bounds__(256) void deg_kernel(const int* __restrict__ src,
    const int* __restrict__ dst, int* __restrict__ outdeg,
    int* __restrict__ indeg, int E)
{
    int i = blockIdx.x * 256 + threadIdx.x;
    if (i < E) {
        atomicAdd(&outdeg[src[i]], 1);
        atomicAdd(&indeg[dst[i]], 1);
    }
}

// inv[i] = rsqrt(max(deg[i],1)) over the whole concatenated degree region
__global__ __launch_bounds__(256) void finalize_deg(const int* __restrict__ deg,
    float* __restrict__ inv, int n)
{
    int i = blockIdx.x * 256 + threadIdx.x;
    if (i < n) {
        float d = (float)deg[i];
        inv[i] = rsqrtf(fmaxf(d, 1.0f));
    }
}

// ---------------- exclusive scan (N <= 65536: P <= 256) ----------------
__global__ __launch_bounds__(256) void scan_partial(const int* __restrict__ deg,
    int* __restrict__ partial, int N)
{
    __shared__ int s[256];
    int gid = blockIdx.x * 256 + threadIdx.x;
    int v = gid < N ? deg[gid] : 0;
    s[threadIdx.x] = v;
    __syncthreads();
    for (int off = 128; off > 0; off >>= 1) {
        if (threadIdx.x < off) s[threadIdx.x] += s[threadIdx.x + off];
        __syncthreads();
    }
    if (threadIdx.x == 0) partial[blockIdx.x] = s[0];
}

__global__ __launch_bounds__(256) void scan_partial_excl(int* __restrict__ partial, int P)
{
    __shared__ int s[256];
    int v = threadIdx.x < P ? partial[threadIdx.x] : 0;
    s[threadIdx.x] = v;
    __syncthreads();
    for (int off = 1; off < 256; off <<= 1) {
        int t = threadIdx.x >= off ? s[threadIdx.x - off] : 0;
        __syncthreads();
        s[threadIdx.x] += t;
        __syncthreads();
    }
    if (threadIdx.x < P) partial[threadIdx.x] = s[threadIdx.x] - v;
}

__global__ __launch_bounds__(256) void scan_final(const int* __restrict__ deg,
    const int* __restrict__ partial, int* __restrict__ row_ptr, int N)
{
    __shared__ int s[256];
    int gid = blockIdx.x * 256 + threadIdx.x;
    int v = gid < N ? deg[gid] : 0;
    s[threadIdx.x] = v;
    __syncthreads();
    for (int off = 1; off < 256; off <<= 1) {
        int t = threadIdx.x >= off ? s[threadIdx.x - off] : 0;
        __syncthreads();
        s[threadIdx.x] += t;
        __syncthreads();
    }
    if (gid < N) {
        int excl = s[threadIdx.x] - v + partial[blockIdx.x];
        row_ptr[gid] = excl;
        if (gid == N - 1) row_ptr[N] = excl + v;
    }
}

// ---------------- CSR fill ----------------
__global__ __launch_bounds__(256) void csr_fill(const int* __restrict__ src,
    const int* __restrict__ dst, const int* __restrict__ row_ptr,
    int* __restrict__ cursor, int* __restrict__ col, int E)
{
    int e = blockIdx.x * 256 + threadIdx.x;
    if (e < E) {
        int d = dst[e];
        int p = atomicAdd(&cursor[d], 1);
        col[row_ptr[d] + p] = src[e];
    }
}

// ---------------- SGEMM: C[M,128] = f(A[M,128]) * inv_s[row] @ W[128,128] ----------------
template <int RELU>
__global__ __launch_bounds__(256) void sgemm128(const float* __restrict__ A,
    const float* __restrict__ W, const float* __restrict__ inv_s,
    float* __restrict__ C, int M)
{
    __shared__ float As[16][65];
    __shared__ float Bs[16][65];
    const int tid  = threadIdx.x;
    const int row0 = blockIdx.x * 64;
    const int col0 = blockIdx.y * 64;
    const int tr = tid >> 4;
    const int tc = tid & 15;
    const int a_row = tid >> 2;
    const int a_k4  = (tid & 3) << 2;
    const int b_krow = tid >> 4;
    const int b_c    = (tid & 15) << 2;

    float acc[4][4] = {};
    const int arow_g = row0 + a_row;
    float scale = 0.0f;
    if (arow_g < M) scale = inv_s[arow_g];

    for (int k0 = 0; k0 < 128; k0 += 16) {
        float4 av = make_float4(0.f, 0.f, 0.f, 0.f);
        if (arow_g < M)
            av = *(const float4*)(A + (size_t)arow_g * 128 + k0 + a_k4);
        if (RELU) {
            av.x = av.x >= 0.f ? av.x : av.x * NEG_SLOPE;
            av.y = av.y >= 0.f ? av.y : av.y * NEG_SLOPE;
            av.z = av.z >= 0.f ? av.z : av.z * NEG_SLOPE;
            av.w = av.w >= 0.f ? av.w : av.w * NEG_SLOPE;
        }
        As[a_k4 + 0][a_row] = av.x * scale;
        As[a_k4 + 1][a_row] = av.y * scale;
        As[a_k4 + 2][a_row] = av.z * scale;
        As[a_k4 + 3][a_row] = av.w * scale;

        float4 bv = *(const float4*)(W + (size_t)(k0 + b_krow) * 128 + col0 + b_c);
        Bs[b_krow][b_c + 0] = bv.x;
        Bs[b_krow][b_c + 1] = bv.y;
        Bs[b_krow][b_c + 2] = bv.z;
        Bs[b_krow][b_c + 3] = bv.w;
        __syncthreads();

#pragma unroll
        for (int k = 0; k < 16; ++k) {
            float ar[4], br[4];
#pragma unroll
            for (int i = 0; i < 4; ++i) ar[i] = As[k][tr * 4 + i];
#pragma unroll
            for (int j = 0; j < 4; ++j) br[j] = Bs[k][tc * 4 + j];
#pragma unroll
            for (int i = 0; i < 4; ++i)
#pragma unroll
                for (int j = 0; j < 4; ++j)
                    acc[i][j] = fmaf(ar[i], br[j], acc[i][j]);
        }
        __syncthreads();
    }

#pragma unroll
    for (int i = 0; i < 4; ++i) {
        int row = row0 + tr * 4 + i;
        if (row < M) {
            float4 v = make_float4(acc[i][0], acc[i][1], acc[i][2], acc[i][3]);
            *(float4*)(C + (size_t)row * 128 + col0 + tc * 4) = v;
        }
    }
}

// ---------------- gather: out[row] = sum_e featA[colA[e]] * invA[row] + biasA
//                                   (+ sum_e featB[colB[e]] * invB[row] + biasB)
// one wave per dst row, float2 per lane, 2-edge unroll for MLP
template <int DUAL>
__global__ __launch_bounds__(256) void gather_rows(
    const float* __restrict__ featA, const int* __restrict__ rpA,
    const int* __restrict__ colA, const float* __restrict__ invA,
    const float* __restrict__ featB, const int* __restrict__ rpB,
    const int* __restrict__ colB, const float* __restrict__ invB,
    const float* __restrict__ biasA, const float* __restrict__ biasB,
    float* __restrict__ out, int Nd)
{
    int lane = threadIdx.x & 63;
    int row = blockIdx.x * 4 + (threadIdx.x >> 6);
    if (row >= Nd) return;
    int c2 = lane * 2;

    float a0 = 0.f, a1 = 0.f;
    {
        int b = rpA[row], e = rpA[row + 1];
        int i = b;
        for (; i + 1 < e; i += 2) {
            float2 v0 = *(const float2*)(featA + (size_t)colA[i] * 128 + c2);
            float2 v1 = *(const float2*)(featA + (size_t)colA[i + 1] * 128 + c2);
            a0 += v0.x + v1.x;
            a1 += v0.y + v1.y;
        }
        if (i < e) {
            float2 v0 = *(const float2*)(featA + (size_t)colA[i] * 128 + c2);
            a0 += v0.x;
            a1 += v0.y;
        }
    }
    float wa = invA[row];
    float r0 = a0 * wa + biasA[c2];
    float r1 = a1 * wa + biasA[c2 + 1];

    if (DUAL) {
        float s0 = 0.f, s1 = 0.f;
        int b = rpB[row], e = rpB[row + 1];
        int i = b;
        for (; i + 1 < e; i += 2) {
            float2 v0 = *(const float2*)(featB + (size_t)colB[i] * 128 + c2);
            float2 v1 = *(const float2*)(featB + (size_t)colB[i + 1] * 128 + c2);
            s0 += v0.x + v1.x;
            s1 += v0.y + v1.y;
        }
        if (i < e) {
            float2 v0 = *(const float2*)(featB + (size_t)colB[i] * 128 + c2);
            s0 += v0.x;
            s1 += v0.y;
        }
        float wb = invB[row];
        r0 += s0 * wb + biasB[c2];
        r1 += s1 * wb + biasB[c2 + 1];
    }
    *(float2*)(out + (size_t)row * 128 + c2) = make_float2(r0, r1);
}

extern "C" void kernel_launch(void* const* d_in, const int* in_sizes, int n_in,
                              void* d_out, int out_size, void* d_ws, size_t ws_size,
                              hipStream_t stream)
{
    const float* x_chem = (const float*)d_in[0];
    const float* x_gene = (const float*)d_in[1];
    const int* src_cc = (const int*)d_in[2];
    const int* dst_cc = (const int*)d_in[3];
    const int* src_cg = (const int*)d_in[4];
    const int* dst_cg = (const int*)d_in[5];
    const int* src_gc = (const int*)d_in[6];
    const int* dst_gc = (const int*)d_in[7];
    const float* W1_cc = (const float*)d_in[8];
    const float* W1_cg = (const float*)d_in[9];
    const float* W1_gc = (const float*)d_in[10];
    const float* W2_cc = (const float*)d_in[11];
    const float* W2_gc = (const float*)d_in[13];
    const float* b1_cc = (const float*)d_in[14];
    const float* b1_cg = (const float*)d_in[15];
    const float* b1_gc = (const float*)d_in[16];
    const float* b2_cc = (const float*)d_in[17];
    const float* b2_gc = (const float*)d_in[19];
    (void)n_in; (void)out_size; (void)ws_size;

    const int Nc = in_sizes[0] / 128;
    const int Ng = in_sizes[1] / 128;
    const int Ecc = in_sizes[2];
    const int Ecg = in_sizes[4];
    const int Egc = in_sizes[6];

    // ---------------- workspace layout ----------------
    // int section (zeroed region first: degrees + cursors)
    int* ip = (int*)d_ws;
    int* deg_src_cc = ip; ip += Nc;
    int* deg_dst_cc = ip; ip += Nc;
    int* deg_src_cg = ip; ip += Nc;
    int* deg_dst_cg = ip; ip += Ng;
    int* deg_src_gc = ip; ip += Ng;
    int* deg_dst_gc = ip; ip += Nc;
    const int degTotal = 4 * Nc + 2 * Ng;
    int* cur_cc = ip; ip += Nc;
    int* cur_cg = ip; ip += Ng;
    int* cur_gc = ip; ip += Nc;
    const size_t zeroInts = (size_t)degTotal + 2 * Nc + Ng;
    // not-zeroed ints
    int* rp_cc = ip; ip += Nc + 1;
    int* rp_cg = ip; ip += Ng + 1;
    int* rp_gc = ip; ip += Nc + 1;
    int* part_cc = ip; ip += 256;
    int* part_cg = ip; ip += 256;
    int* part_gc = ip; ip += 256;
    int* col_cc = ip; ip += Ecc;
    int* col_cg = ip; ip += Ecg;
    int* col_gc = ip; ip += Egc;
    // float section (align to 16 B)
    size_t intCount = (size_t)(ip - (int*)d_ws);
    intCount = (intCount + 3) & ~(size_t)3;
    float* fp = (float*)d_ws + intCount;
    float* inv = fp; fp += degTotal;  // same order as degree arrays
    float* inv_src_cc = inv;
    float* inv_dst_cc = inv + Nc;
    float* inv_src_cg = inv + 2 * Nc;
    float* inv_dst_cg = inv + 3 * Nc;
    float* inv_src_gc = inv + 3 * Nc + Ng;
    float* inv_dst_gc = inv + 3 * Nc + 2 * Ng;
    float* h1_chem = fp; fp += (size_t)Nc * 128;
    float* h1_gene = fp; fp += (size_t)Ng * 128;
    float* tmpA    = fp; fp += (size_t)Nc * 128;
    float* tmpB    = fp; fp += (size_t)Nc * 128;  // holds up to Nc rows (used for Ng too)
    float* out = (float*)d_out;

    hipMemsetAsync(d_ws, 0, zeroInts * sizeof(int), stream);

    dim3 blk(256);
    // degrees
    deg_kernel<<<(Ecc + 255) / 256, blk, 0, stream>>>(src_cc, dst_cc, deg_src_cc, deg_dst_cc, Ecc);
    deg_kernel<<<(Ecg + 255) / 256, blk, 0, stream>>>(src_cg, dst_cg, deg_src_cg, deg_dst_cg, Ecg);
    deg_kernel<<<(Egc + 255) / 256, blk, 0, stream>>>(src_gc, dst_gc, deg_src_gc, deg_dst_gc, Egc);
    finalize_deg<<<(degTotal + 255) / 256, blk, 0, stream>>>(deg_src_cc, inv, degTotal);

    // CSR build per relation (dst-major)
    const int Pcc = (Nc + 255) / 256, Pcg = (Ng + 255) / 256;
    scan_partial<<<Pcc, blk, 0, stream>>>(deg_dst_cc, part_cc, Nc);
    scan_partial<<<Pcg, blk, 0, stream>>>(deg_dst_cg, part_cg, Ng);
    scan_partial<<<Pcc, blk, 0, stream>>>(deg_dst_gc, part_gc, Nc);
    scan_partial_excl<<<1, blk, 0, stream>>>(part_cc, Pcc);
    scan_partial_excl<<<1, blk, 0, stream>>>(part_cg, Pcg);
    scan_partial_excl<<<1, blk, 0, stream>>>(part_gc, Pcc);
    scan_final<<<Pcc, blk, 0, stream>>>(deg_dst_cc, part_cc, rp_cc, Nc);
    scan_final<<<Pcg, blk, 0, stream>>>(deg_dst_cg, part_cg, rp_cg, Ng);
    scan_final<<<Pcc, blk, 0, stream>>>(deg_dst_gc, part_gc, rp_gc, Nc);
    csr_fill<<<(Ecc + 255) / 256, blk, 0, stream>>>(src_cc, dst_cc, rp_cc, cur_cc, col_cc, Ecc);
    csr_fill<<<(Ecg + 255) / 256, blk, 0, stream>>>(src_cg, dst_cg, rp_cg, cur_cg, col_cg, Ecg);
    csr_fill<<<(Egc + 255) / 256, blk, 0, stream>>>(src_gc, dst_gc, rp_gc, cur_gc, col_gc, Egc);

    // ---- layer 1 ----
    // h1_gene = gather_cg(xc @ W1_cg) + b1_cg
    sgemm128<0><<<dim3((Nc + 63) / 64, 2), blk, 0, stream>>>(x_chem, W1_cg, inv_src_cg, tmpA, Nc);
    gather_rows<0><<<(Ng + 3) / 4, blk, 0, stream>>>(tmpA, rp_cg, col_cg, inv_dst_cg,
        nullptr, nullptr, nullptr, nullptr, b1_cg, nullptr, h1_gene, Ng);

    // h1_chem = gather_cc(xc @ W1_cc) + b1_cc + gather_gc(xg @ W1_gc) + b1_gc
    sgemm128<0><<<dim3((Nc + 63) / 64, 2), blk, 0, stream>>>(x_chem, W1_cc, inv_src_cc, tmpA, Nc);
    sgemm128<0><<<dim3((Ng + 63) / 64, 2), blk, 0, stream>>>(x_gene, W1_gc, inv_src_gc, tmpB, Ng);
    gather_rows<1><<<(Nc + 3) / 4, blk, 0, stream>>>(tmpA, rp_cc, col_cc, inv_dst_cc,
        tmpB, rp_gc, col_gc, inv_dst_gc, b1_cc, b1_gc, h1_chem, Nc);

    // ---- layer 2 (leaky-relu fused into GEMM A-load) ----
    sgemm128<1><<<dim3((Nc + 63) / 64, 2), blk, 0, stream>>>(h1_chem, W2_cc, inv_src_cc, tmpA, Nc);
    sgemm128<1><<<dim3((Ng + 63) / 64, 2), blk, 0, stream>>>(h1_gene, W2_gc, inv_src_gc, tmpB, Ng);
    gather_rows<1><<<(Nc + 3) / 4, blk, 0, stream>>>(tmpA, rp_cc, col_cc, inv_dst_cc,
        tmpB, rp_gc, col_gc, inv_dst_gc, b2_cc, b2_gc, out, Nc);
}